// Round 1
// baseline (422.150 us; speedup 1.0000x reference)
//
#include <hip/hip_runtime.h>
#include <math.h>

#define B_ 32
#define L_ 8192
#define D_ 256
#define M_ 4097   // L/2 + 1

// ---------------------------------------------------------------------------
// K1: s[b,l] = sigmoid(dot(x[b,l,:], W) + bias).  One wave (64 lanes) per row,
// each lane loads a float4 of x and W (64*4 = 256 = D), shuffle-xor reduce.
// ---------------------------------------------------------------------------
__global__ __launch_bounds__(256) void k_sigmoid_dot(
    const float* __restrict__ x, const float* __restrict__ W,
    const float* __restrict__ bias, float* __restrict__ s)
{
    int row  = (blockIdx.x << 2) + (threadIdx.x >> 6);   // 4 waves/block
    int lane = threadIdx.x & 63;
    const float4 xv = ((const float4*)(x + (size_t)row * D_))[lane];
    const float4 wv = ((const float4*)W)[lane];
    float p = xv.x * wv.x + xv.y * wv.y + xv.z * wv.z + xv.w * wv.w;
#pragma unroll
    for (int off = 32; off > 0; off >>= 1)
        p += __shfl_xor(p, off, 64);
    if (lane == 0) {
        float z = p + bias[0];
        s[row] = 1.0f / (1.0f + expf(-z));
    }
}

// ---------------------------------------------------------------------------
// K2: per batch: strict-local-min mask (zero-padded neighbors, frame 0 forced
// true), block-wide scan for prefix ranks, compact starts, emit counts.
// One block (256 threads) per batch; each thread owns 32 contiguous frames.
// ---------------------------------------------------------------------------
__global__ __launch_bounds__(256) void k_scan(
    const float* __restrict__ s, int* __restrict__ starts,
    int* __restrict__ counts, float* __restrict__ out_counts)
{
    int b = blockIdx.x;
    const float* sb = s + (size_t)b * L_;
    int t    = threadIdx.x;
    int base = t * 32;

    unsigned bits = 0;
    int cnt = 0;
    float sprev = (base == 0) ? 0.0f : sb[base - 1];
    float sc    = sb[base];
#pragma unroll 1
    for (int i = 0; i < 32; i++) {
        int l = base + i;
        float snext = (l == L_ - 1) ? 0.0f : sb[l + 1];
        bool m = (l == 0) ? true : ((sc < sprev) && (sc < snext));
        if (m) { bits |= (1u << i); cnt++; }
        sprev = sc;
        sc    = snext;
    }

    __shared__ int sh[256];
    sh[t] = cnt;
    __syncthreads();
    for (int off = 1; off < 256; off <<= 1) {     // Hillis-Steele inclusive
        int v = (t >= off) ? sh[t - off] : 0;
        __syncthreads();
        sh[t] += v;
        __syncthreads();
    }
    int excl  = sh[t] - cnt;
    int total = sh[255];

    int k = excl;
    for (int i = 0; i < 32; i++) {
        if (bits & (1u << i)) { starts[b * M_ + k] = base + i; k++; }
    }
    if (t == 0) {
        counts[b]     = total;
        out_counts[b] = (float)total;   // harness reads flat out buffer as f32
    }
}

// ---------------------------------------------------------------------------
// K3: one wave per output row (b,k).  k >= count -> zeros (d_out is poisoned
// before every timed launch).  Else gather x rows p, p+1 and blend.
// ---------------------------------------------------------------------------
__global__ __launch_bounds__(64) void k_write(
    const float* __restrict__ x, const float* __restrict__ s,
    const int* __restrict__ starts, const int* __restrict__ counts,
    float* __restrict__ out)
{
    int k    = blockIdx.x;
    int b    = blockIdx.y;
    int lane = threadIdx.x;
    float4* orow = (float4*)(out + ((size_t)b * M_ + k) * D_);
    if (k >= counts[b]) {
        orow[lane] = make_float4(0.f, 0.f, 0.f, 0.f);
        return;
    }
    int p = starts[b * M_ + k];
    const float* sb = s + (size_t)b * L_;
    float s0 = sb[p];
    bool has1 = (p + 1 < L_);
    float s1 = has1 ? sb[p + 1] : 0.0f;
    float inv = 1.0f / fmaxf(s0 + s1, 1e-6f);

    const float4* x0 = (const float4*)(x + ((size_t)b * L_ + p) * D_);
    float4 a = x0[lane];
    float4 r;
    r.x = s0 * a.x; r.y = s0 * a.y; r.z = s0 * a.z; r.w = s0 * a.w;
    if (has1) {
        float4 c = (x0 + (D_ / 4))[lane];
        r.x += s1 * c.x; r.y += s1 * c.y; r.z += s1 * c.z; r.w += s1 * c.w;
    }
    r.x *= inv; r.y *= inv; r.z *= inv; r.w *= inv;
    orow[lane] = r;
}

extern "C" void kernel_launch(void* const* d_in, const int* in_sizes, int n_in,
                              void* d_out, int out_size, void* d_ws, size_t ws_size,
                              hipStream_t stream) {
    const float* x    = (const float*)d_in[0];
    // d_in[1] = olens: unused by the reference
    const float* W    = (const float*)d_in[2];
    const float* bias = (const float*)d_in[3];

    float* out        = (float*)d_out;
    float* out_counts = out + (size_t)B_ * M_ * D_;   // counts tail, as f32

    float* s      = (float*)d_ws;                                   // B*L f32 (1 MB)
    int*   starts = (int*)((char*)d_ws + (size_t)B_ * L_ * 4);      // B*M i32
    int*   counts = (int*)((char*)starts + (size_t)B_ * M_ * 4);    // B   i32

    k_sigmoid_dot<<<(B_ * L_) / 4, 256, 0, stream>>>(x, W, bias, s);
    k_scan<<<B_, 256, 0, stream>>>(s, starts, counts, out_counts);
    k_write<<<dim3(M_, B_), 64, 0, stream>>>(x, s, starts, counts, out);
}